// Round 1
// baseline (94.015 us; speedup 1.0000x reference)
//
#include <hip/hip_runtime.h>
#include <math.h>
#include <float.h>

// Zonotope distance + gradient.
// One 64-lane wave per point. H=48 hyperplanes, V=96 edges.
// LDS: per-wave float4[48] (xyz = A row, w = b).

constexpr int H = 48;
constexpr int V = 96;
constexpr int WPB = 4;          // waves per block
constexpr float ZEPS = 1e-4f;

__global__ __launch_bounds__(256) void zono_dist_kernel(
    const float* __restrict__ point,   // [N,3]
    const float* __restrict__ Ag,      // [N,H,3]
    const float* __restrict__ bg,      // [N,H]
    const float* __restrict__ v1g,     // [N,V,3]
    const float* __restrict__ v2g,     // [N,V,3]
    float* __restrict__ out,           // [N] dist ++ [N,3] grad
    int N)
{
#pragma clang fp contract(off)
  // contract(off): the on-zonotope test (s <= EPS) is boundary-sensitive;
  // we must match the numpy reference's mul/add rounding exactly.
  __shared__ float4 sAb[WPB][H];

  const int wave = threadIdx.x >> 6;
  const int lane = threadIdx.x & 63;
  const int n = blockIdx.x * WPB + wave;
  if (n >= N) return;

  const float px = point[3 * (size_t)n + 0];
  const float py = point[3 * (size_t)n + 1];
  const float pz = point[3 * (size_t)n + 2];

  // ---- stage A,b into LDS ----
  if (lane < H) {
    const float* ap = Ag + (size_t)n * (H * 3) + lane * 3;
    float4 r;
    r.x = ap[0];
    r.y = ap[1];
    r.z = ap[2];
    r.w = bg[(size_t)n * H + lane];
    sAb[wave][lane] = r;
  }
  __syncthreads();

  // ---- signed facet offsets Apb[h] ----
  float apb = -INFINITY;
  float ax = 0.f, ay = 0.f, az = 0.f;
  if (lane < H) {
    float4 ab = sAb[wave][lane];
    ax = ab.x; ay = ab.y; az = ab.z;
    float s = ax * px + ay * py + az * pz - ab.w;
    if (!isfinite(s)) s = -INFINITY;
    apb = s;
  }

  const bool is_neg = (bool)__all(apb <= 0.0f);   // lanes >= H hold -inf -> true

  // max + argmax (first-max tiebreak -> lower index)
  float nv = apb;
  int ni = (lane < H) ? lane : 0x7FFFFFFF;
  #pragma unroll
  for (int off = 32; off; off >>= 1) {
    float ov = __shfl_xor(nv, off);
    int oi = __shfl_xor(ni, off);
    if (ov > nv || (ov == nv && oi < ni)) { nv = ov; ni = oi; }
  }

  // ---- face (perpendicular) distances ----
  float perp = INFINITY;
  if (lane < H) {
    // projection onto plane h (exact ref op order: mul then sub)
    float qx = px - apb * ax;
    float qy = py - apb * ay;
    float qz = pz - apb * az;
    bool onz = true;
    for (int k = 0; k < H; ++k) {
      float4 ab = sAb[wave][k];
      float s = ab.x * qx + ab.y * qy + ab.z * qz - ab.w;
      // finite inputs -> s always finite; ref's isfinite cleanup is a no-op here
      onz = onz && (s <= ZEPS);
    }
    float dx = px - qx, dy = py - qy, dz = pz - qz;   // match ref: p - proj
    float pp = sqrtf(dx * dx + dy * dy + dz * dz);
    perp = onz ? pp : INFINITY;
    if (isnan(perp)) perp = INFINITY;
  }
  float fv = perp;
  int fi = (lane < H) ? lane : 0x7FFFFFFF;
  #pragma unroll
  for (int off = 32; off; off >>= 1) {
    float ov = __shfl_xor(fv, off);
    int oi = __shfl_xor(fi, off);
    if (ov < fv || (ov == fv && oi < fi)) { fv = ov; fi = oi; }
  }
  // fv==inf everywhere ties down to fi==0, matching argmin-of-all-inf -> 0

  // ---- edge (segment) distances ----
  float bed = INFINITY;
  int bei = 0x7FFFFFFF;
  float bvx = 0.f, bvy = 0.f, bvz = 0.f;
  const float* v1p = v1g + (size_t)n * (V * 3);
  const float* v2p = v2g + (size_t)n * (V * 3);
  #pragma unroll
  for (int r = 0; r < 2; ++r) {
    int e = lane + r * 64;
    if (e < V) {
      float x1 = v1p[3 * e + 0], y1 = v1p[3 * e + 1], z1 = v1p[3 * e + 2];
      float x2 = v2p[3 * e + 0], y2 = v2p[3 * e + 1], z2 = v2p[3 * e + 2];
      float dx = x2 - x1, dy = y2 - y1, dz = z2 - z1;
      float denom = dx * dx + dy * dy + dz * dz;
      float wx = px - x1, wy = py - y1, wz = pz - z1;
      float th = (wx * dx + wy * dy + wz * dz) / denom;
      // NaN-propagating clip (matches jnp.clip)
      float ts = th < 0.0f ? 0.0f : (th > 1.0f ? 1.0f : th);
      float vx = x1 + ts * dx, vy = y1 + ts * dy, vz = z1 + ts * dz;
      float ex = px - vx, ey = py - vy, ez = pz - vz;
      float ed = sqrtf(ex * ex + ey * ey + ez * ez);
      if (isnan(ed)) ed = INFINITY;
      if (ed < bed || (ed == bed && e < bei)) {
        bed = ed; bei = e; bvx = vx; bvy = vy; bvz = vz;
      }
    }
  }
  #pragma unroll
  for (int off = 32; off; off >>= 1) {
    float ov = __shfl_xor(bed, off);
    int oi = __shfl_xor(bei, off);
    float ox = __shfl_xor(bvx, off);
    float oy = __shfl_xor(bvy, off);
    float oz = __shfl_xor(bvz, off);
    if (ov < bed || (ov == bed && oi < bei)) {
      bed = ov; bei = oi; bvx = ox; bvy = oy; bvz = oz;
    }
  }

  // ---- combine & write (lane 0) ----
  if (lane == 0) {
    float dist, gx, gy, gz;
    if (is_neg) {
      float4 g = sAb[wave][ni];
      dist = nv; gx = g.x; gy = g.y; gz = g.z;
    } else if (bed < fv) {
      dist = bed;
      gx = (px - bvx) / bed;
      gy = (py - bvy) / bed;
      gz = (pz - bvz) / bed;
    } else {
      float4 g = sAb[wave][fi];
      dist = fv; gx = g.x; gy = g.y; gz = g.z;
    }
    out[n] = dist;
    out[(size_t)N + 3 * (size_t)n + 0] = gx;
    out[(size_t)N + 3 * (size_t)n + 1] = gy;
    out[(size_t)N + 3 * (size_t)n + 2] = gz;
  }
}

extern "C" void kernel_launch(void* const* d_in, const int* in_sizes, int n_in,
                              void* d_out, int out_size, void* d_ws, size_t ws_size,
                              hipStream_t stream) {
  const float* point = (const float*)d_in[0];
  const float* Ag    = (const float*)d_in[1];
  const float* bg    = (const float*)d_in[2];
  const float* v1g   = (const float*)d_in[3];
  const float* v2g   = (const float*)d_in[4];
  float* out = (float*)d_out;

  const int N = in_sizes[0] / 3;
  const int blocks = (N + WPB - 1) / WPB;
  zono_dist_kernel<<<blocks, WPB * 64, 0, stream>>>(point, Ag, bg, v1g, v2g, out, N);
}

// Round 2
// 74.787 us; speedup vs baseline: 1.2571x; 1.2571x over previous
//
#include <hip/hip_runtime.h>
#include <math.h>
#include <float.h>

// Zonotope distance + gradient. One 64-lane wave per point.
// H=48 hyperplanes, V=96 edges.
// Transposed on-zono check: lane k holds plane k in registers; loop over
// candidate h reading projection q[h] from LDS (broadcast). on_zono via
// __all -> SALU bitmask. Face/neg reductions gated (rare for random data).
// ALL floating-point op orders match the numpy reference exactly
// (contract(off); no FMA) — the EPS / argmin boundaries are flip-sensitive.

typedef float f32x2 __attribute__((ext_vector_type(2)));

constexpr int H = 48;
constexpr int V = 96;
constexpr int WPB = 4;          // waves per block
constexpr float ZEPS = 1e-4f;

__global__ __launch_bounds__(256) void zono_dist_kernel(
    const float* __restrict__ point,   // [N,3]
    const float* __restrict__ Ag,      // [N,H,3]
    const float* __restrict__ bg,      // [N,H]
    const float* __restrict__ v1g,     // [N,V,3]
    const float* __restrict__ v2g,     // [N,V,3]
    float* __restrict__ out,           // [N] dist ++ [N,3] grad
    int N)
{
#pragma clang fp contract(off)
  __shared__ __align__(16) float sQx[WPB][H];
  __shared__ __align__(16) float sQy[WPB][H];
  __shared__ __align__(16) float sQz[WPB][H];

  const int wave = threadIdx.x >> 6;
  const int lane = threadIdx.x & 63;
  const int n = blockIdx.x * WPB + wave;
  if (n >= N) return;

  const float px = point[3 * (size_t)n + 0];
  const float py = point[3 * (size_t)n + 1];
  const float pz = point[3 * (size_t)n + 2];

  // ---- own plane in registers (lane k = plane k) ----
  float ax = 0.f, ay = 0.f, az = 0.f, bb = 1e30f;  // lanes >=H: s = -1e30 <= EPS, neutral
  if (lane < H) {
    const float* ap = Ag + (size_t)n * (H * 3) + lane * 3;
    ax = ap[0]; ay = ap[1]; az = ap[2];
    bb = bg[(size_t)n * H + lane];
  }

  // ---- signed facet offset + projection (exact ref op order) ----
  float apb = -INFINITY;
  float qx = 0.f, qy = 0.f, qz = 0.f;
  if (lane < H) {
    apb = ((ax * px + ay * py) + az * pz) - bb;   // finite for finite inputs
    qx = px - apb * ax;
    qy = py - apb * ay;
    qz = pz - apb * az;
    sQx[wave][lane] = qx;
    sQy[wave][lane] = qy;
    sQz[wave][lane] = qz;
  }
  const bool is_neg = (bool)__all(apb <= 0.0f);

  // ---- on-zonotope check, transposed: all 48 k-checks of candidate h at once ----
  const f32x2 axx = {ax, ax}, ayy = {ay, ay}, azz = {az, az}, bb2 = {bb, bb};
  unsigned long long bad = 0;           // bit h set => on_zono[h] false
  #pragma unroll 8
  for (int h = 0; h < H; h += 2) {
    f32x2 qx2 = *(const f32x2*)&sQx[wave][h];   // broadcast reads (same addr all lanes)
    f32x2 qy2 = *(const f32x2*)&sQy[wave][h];
    f32x2 qz2 = *(const f32x2*)&sQz[wave][h];
    f32x2 s = ((axx * qx2 + ayy * qy2) + azz * qz2) - bb2;  // ref einsum order
    unsigned long long b0 = (unsigned long long)(!__all(s.x <= ZEPS));
    unsigned long long b1 = (unsigned long long)(!__all(s.y <= ZEPS));
    bad |= (b0 << h) | (b1 << (h + 1));
  }
  const unsigned long long MASK48 = (1ull << H) - 1;
  const bool any_face = ((~bad) & MASK48) != 0;

  // ---- face distance (rare path for random data) ----
  float fv = INFINITY; int fi = 0;
  float fgx = 0.f, fgy = 0.f, fgz = 0.f;
  if (any_face) {
    float pv = INFINITY;
    if (lane < H && !((bad >> lane) & 1)) {
      float dx = px - qx, dy = py - qy, dz = pz - qz;   // ref: p - proj
      pv = sqrtf((dx * dx + dy * dy) + dz * dz);
    }
    fv = pv; fi = lane;
    #pragma unroll
    for (int off = 32; off; off >>= 1) {
      float ov = __shfl_xor(fv, off);
      int oi = __shfl_xor(fi, off);
      if (ov < fv || (ov == fv && oi < fi)) { fv = ov; fi = oi; }
    }
    fgx = __shfl(ax, fi); fgy = __shfl(ay, fi); fgz = __shfl(az, fi);
  }

  // ---- inside-zonotope path (rare) ----
  float nv = 0.f;
  float ngx = 0.f, ngy = 0.f, ngz = 0.f;
  if (is_neg) {
    nv = apb; int ni = lane;
    #pragma unroll
    for (int off = 32; off; off >>= 1) {
      float ov = __shfl_xor(nv, off);
      int oi = __shfl_xor(ni, off);
      if (ov > nv || (ov == nv && oi < ni)) { nv = ov; ni = oi; }
    }
    ngx = __shfl(ax, ni); ngy = __shfl(ay, ni); ngz = __shfl(az, ni);
  }

  // ---- edge (segment) distances ----
  float bed = INFINITY;
  int bei = 0x7FFFFFFF;
  float bvx = 0.f, bvy = 0.f, bvz = 0.f;
  const float* v1p = v1g + (size_t)n * (V * 3);
  const float* v2p = v2g + (size_t)n * (V * 3);
  #pragma unroll
  for (int r = 0; r < 2; ++r) {
    int e = lane + r * 64;
    if (e < V) {
      float x1 = v1p[3 * e + 0], y1 = v1p[3 * e + 1], z1 = v1p[3 * e + 2];
      float x2 = v2p[3 * e + 0], y2 = v2p[3 * e + 1], z2 = v2p[3 * e + 2];
      float dx = x2 - x1, dy = y2 - y1, dz = z2 - z1;
      float denom = (dx * dx + dy * dy) + dz * dz;
      float wx = px - x1, wy = py - y1, wz = pz - z1;
      float th = ((wx * dx + wy * dy) + wz * dz) / denom;
      float ts = th < 0.0f ? 0.0f : (th > 1.0f ? 1.0f : th);
      float vx = x1 + ts * dx, vy = y1 + ts * dy, vz = z1 + ts * dz;
      float ex = px - vx, ey = py - vy, ez = pz - vz;
      float ed = sqrtf((ex * ex + ey * ey) + ez * ez);
      if (ed < bed || (ed == bed && e < bei)) {
        bed = ed; bei = e; bvx = vx; bvy = vy; bvz = vz;
      }
    }
  }
  #pragma unroll
  for (int off = 32; off; off >>= 1) {
    float ov = __shfl_xor(bed, off);
    int oi = __shfl_xor(bei, off);
    if (ov < bed || (ov == bed && oi < bei)) { bed = ov; bei = oi; }
  }
  // fetch winner's closest point (winner lane = bei & 63; bei is wave-uniform now)
  const int wl = bei & 63;
  const float wvx = __shfl(bvx, wl);
  const float wvy = __shfl(bvy, wl);
  const float wvz = __shfl(bvz, wl);

  // ---- combine & write (lane 0) ----
  if (lane == 0) {
    float dist, gx, gy, gz;
    if (is_neg) {
      dist = nv; gx = ngx; gy = ngy; gz = ngz;
    } else if (bed < fv) {
      dist = bed;
      gx = (px - wvx) / bed;
      gy = (py - wvy) / bed;
      gz = (pz - wvz) / bed;
    } else {
      dist = fv; gx = fgx; gy = fgy; gz = fgz;
    }
    out[n] = dist;
    out[(size_t)N + 3 * (size_t)n + 0] = gx;
    out[(size_t)N + 3 * (size_t)n + 1] = gy;
    out[(size_t)N + 3 * (size_t)n + 2] = gz;
  }
}

extern "C" void kernel_launch(void* const* d_in, const int* in_sizes, int n_in,
                              void* d_out, int out_size, void* d_ws, size_t ws_size,
                              hipStream_t stream) {
  const float* point = (const float*)d_in[0];
  const float* Ag    = (const float*)d_in[1];
  const float* bg    = (const float*)d_in[2];
  const float* v1g   = (const float*)d_in[3];
  const float* v2g   = (const float*)d_in[4];
  float* out = (float*)d_out;

  const int N = in_sizes[0] / 3;
  const int blocks = (N + WPB - 1) / WPB;
  zono_dist_kernel<<<blocks, WPB * 64, 0, stream>>>(point, Ag, bg, v1g, v2g, out, N);
}

// Round 3
// 61.874 us; speedup vs baseline: 1.5195x; 1.2087x over previous
//
#include <hip/hip_runtime.h>
#include <math.h>
#include <float.h>

// Zonotope distance + gradient. One 64-lane wave per point.
// H=48 hyperplanes, V=96 edges.
// R3: all global reads coalesced dwordx4 via LDS staging; point via s_load;
// edge payload held in registers across the H^2 loop (issue-early/write-late).
// ALL floating-point op orders match the numpy reference exactly
// (contract(off); no FMA) — the EPS / argmin boundaries are flip-sensitive.

typedef float f32x4 __attribute__((ext_vector_type(4)));

constexpr int H = 48;
constexpr int V = 96;
constexpr int WPB = 4;          // waves per block
constexpr float ZEPS = 1e-4f;

__global__ __launch_bounds__(256) void zono_dist_kernel(
    const float* __restrict__ point,   // [N,3]
    const float* __restrict__ Ag,      // [N,H,3]
    const float* __restrict__ bg,      // [N,H]
    const float* __restrict__ v1g,     // [N,V,3]
    const float* __restrict__ v2g,     // [N,V,3]
    float* __restrict__ out,           // [N] dist ++ [N,3] grad
    int N)
{
#pragma clang fp contract(off)
  __shared__ __align__(16) float sAb[WPB][192];   // A[48*3] ++ b[48]
  __shared__ __align__(16) float sQx[WPB][48];
  __shared__ __align__(16) float sQy[WPB][48];
  __shared__ __align__(16) float sQz[WPB][48];
  __shared__ __align__(16) float sEV[WPB][576];   // v1[96*3] ++ v2[96*3]

  const int wave = threadIdx.x >> 6;
  const int lane = threadIdx.x & 63;
  const int n = blockIdx.x * WPB + wave;
  if (n >= N) return;
  const int nu = __builtin_amdgcn_readfirstlane(n);   // wave-uniform -> s_load paths

  // ---- point via scalar loads (uniform address) ----
  const float px = point[3 * (size_t)nu + 0];
  const float py = point[3 * (size_t)nu + 1];
  const float pz = point[3 * (size_t)nu + 2];

  // ---- coalesced staging: A (36 float4) + b (12 float4) -> LDS ----
  {
    const float4* Af4 = (const float4*)(Ag + (size_t)nu * (H * 3));
    const float4* Bf4 = (const float4*)(bg + (size_t)nu * H);
    float4* dst = (float4*)sAb[wave];
    if (lane < 36)      dst[lane] = Af4[lane];
    else if (lane < 48) dst[lane] = Bf4[lane - 36];
  }

  // ---- edge payload: 144 float4 loaded coalesced into REGISTERS now,
  //      written to LDS after the H^2 loop (latency hides under compute) ----
  const float4* V1f4 = (const float4*)(v1g + (size_t)nu * (V * 3));
  const float4* V2f4 = (const float4*)(v2g + (size_t)nu * (V * 3));
  float4 ev0 = V1f4[lane];                                   // slots 0..63   (v1)
  float4 ev1;                                                // slots 64..127
  if (lane < 8) ev1 = V1f4[64 + lane]; else ev1 = V2f4[lane - 8];
  float4 ev2 = {0.f, 0.f, 0.f, 0.f};                         // slots 128..143
  if (lane < 16) ev2 = V2f4[56 + lane];

  // ---- own plane from LDS ----
  float ax = 0.f, ay = 0.f, az = 0.f, bb = 1e30f;  // lanes >=H neutral
  if (lane < H) {
    ax = sAb[wave][3 * lane + 0];
    ay = sAb[wave][3 * lane + 1];
    az = sAb[wave][3 * lane + 2];
    bb = sAb[wave][144 + lane];
  }

  // ---- signed facet offset + projection (exact ref op order) ----
  float apb = -INFINITY;
  float qx = 0.f, qy = 0.f, qz = 0.f;
  if (lane < H) {
    apb = ((ax * px + ay * py) + az * pz) - bb;
    qx = px - apb * ax;
    qy = py - apb * ay;
    qz = pz - apb * az;
    sQx[wave][lane] = qx;
    sQy[wave][lane] = qy;
    sQz[wave][lane] = qz;
  }
  const bool is_neg = (bool)__all(apb <= 0.0f);

  // ---- on-zonotope check, transposed: lane k holds plane k; loop h (x4) ----
  const f32x4 ax4 = {ax, ax, ax, ax}, ay4 = {ay, ay, ay, ay},
              az4 = {az, az, az, az}, bb4 = {bb, bb, bb, bb};
  unsigned long long bad = 0;           // bit h set => on_zono[h] false
  #pragma unroll
  for (int h = 0; h < H; h += 4) {
    f32x4 qx4 = *(const f32x4*)&sQx[wave][h];   // broadcast reads
    f32x4 qy4 = *(const f32x4*)&sQy[wave][h];
    f32x4 qz4 = *(const f32x4*)&sQz[wave][h];
    f32x4 s = ((ax4 * qx4 + ay4 * qy4) + az4 * qz4) - bb4;  // ref einsum order
    unsigned long long b0 = (unsigned long long)(!__all(s.x <= ZEPS));
    unsigned long long b1 = (unsigned long long)(!__all(s.y <= ZEPS));
    unsigned long long b2 = (unsigned long long)(!__all(s.z <= ZEPS));
    unsigned long long b3 = (unsigned long long)(!__all(s.w <= ZEPS));
    bad |= (b0 << h) | (b1 << (h + 1)) | (b2 << (h + 2)) | (b3 << (h + 3));
  }
  const unsigned long long MASK48 = (1ull << H) - 1;
  const bool any_face = ((~bad) & MASK48) != 0;

  // ---- face distance ----
  float fv = INFINITY; int fi = 0;
  float fgx = 0.f, fgy = 0.f, fgz = 0.f;
  if (any_face) {
    float pv = INFINITY;
    if (lane < H && !((bad >> lane) & 1)) {
      float dx = px - qx, dy = py - qy, dz = pz - qz;   // ref: p - proj
      pv = sqrtf((dx * dx + dy * dy) + dz * dz);
    }
    fv = pv; fi = lane;
    #pragma unroll
    for (int off = 32; off; off >>= 1) {
      float ov = __shfl_xor(fv, off);
      int oi = __shfl_xor(fi, off);
      if (ov < fv || (ov == fv && oi < fi)) { fv = ov; fi = oi; }
    }
    fgx = __shfl(ax, fi); fgy = __shfl(ay, fi); fgz = __shfl(az, fi);
  }

  // ---- inside-zonotope path (rare) ----
  float nv = 0.f;
  float ngx = 0.f, ngy = 0.f, ngz = 0.f;
  if (is_neg) {
    nv = apb; int ni = lane;
    #pragma unroll
    for (int off = 32; off; off >>= 1) {
      float ov = __shfl_xor(nv, off);
      int oi = __shfl_xor(ni, off);
      if (ov > nv || (ov == nv && oi < ni)) { nv = ov; ni = oi; }
    }
    ngx = __shfl(ax, ni); ngy = __shfl(ay, ni); ngz = __shfl(az, ni);
  }

  // ---- write staged edge payload to LDS (loads have been in flight) ----
  {
    float4* evp = (float4*)sEV[wave];
    evp[lane] = ev0;
    evp[64 + lane] = ev1;
    if (lane < 16) evp[128 + lane] = ev2;
  }

  // ---- edge (segment) distances, from LDS ----
  float bed = INFINITY;
  int bei = 0x7FFFFFFF;
  float bvx = 0.f, bvy = 0.f, bvz = 0.f;
  const float* ev = sEV[wave];
  #pragma unroll
  for (int r = 0; r < 2; ++r) {
    int e = lane + r * 64;
    if (e < V) {
      float x1 = ev[3 * e + 0], y1 = ev[3 * e + 1], z1 = ev[3 * e + 2];
      float x2 = ev[288 + 3 * e + 0], y2 = ev[288 + 3 * e + 1], z2 = ev[288 + 3 * e + 2];
      float dx = x2 - x1, dy = y2 - y1, dz = z2 - z1;
      float denom = (dx * dx + dy * dy) + dz * dz;
      float wx = px - x1, wy = py - y1, wz = pz - z1;
      float th = ((wx * dx + wy * dy) + wz * dz) / denom;
      float ts = th < 0.0f ? 0.0f : (th > 1.0f ? 1.0f : th);
      float vx = x1 + ts * dx, vy = y1 + ts * dy, vz = z1 + ts * dz;
      float ex = px - vx, ey = py - vy, ez = pz - vz;
      float ed = sqrtf((ex * ex + ey * ey) + ez * ez);
      if (ed < bed || (ed == bed && e < bei)) {
        bed = ed; bei = e; bvx = vx; bvy = vy; bvz = vz;
      }
    }
  }
  #pragma unroll
  for (int off = 32; off; off >>= 1) {
    float ov = __shfl_xor(bed, off);
    int oi = __shfl_xor(bei, off);
    if (ov < bed || (ov == bed && oi < bei)) { bed = ov; bei = oi; }
  }
  const int wl = bei & 63;
  const float wvx = __shfl(bvx, wl);
  const float wvy = __shfl(bvy, wl);
  const float wvz = __shfl(bvz, wl);

  // ---- combine & write (lane 0) ----
  if (lane == 0) {
    float dist, gx, gy, gz;
    if (is_neg) {
      dist = nv; gx = ngx; gy = ngy; gz = ngz;
    } else if (bed < fv) {
      dist = bed;
      gx = (px - wvx) / bed;
      gy = (py - wvy) / bed;
      gz = (pz - wvz) / bed;
    } else {
      dist = fv; gx = fgx; gy = fgy; gz = fgz;
    }
    out[n] = dist;
    out[(size_t)N + 3 * (size_t)n + 0] = gx;
    out[(size_t)N + 3 * (size_t)n + 1] = gy;
    out[(size_t)N + 3 * (size_t)n + 2] = gz;
  }
}

extern "C" void kernel_launch(void* const* d_in, const int* in_sizes, int n_in,
                              void* d_out, int out_size, void* d_ws, size_t ws_size,
                              hipStream_t stream) {
  const float* point = (const float*)d_in[0];
  const float* Ag    = (const float*)d_in[1];
  const float* bg    = (const float*)d_in[2];
  const float* v1g   = (const float*)d_in[3];
  const float* v2g   = (const float*)d_in[4];
  float* out = (float*)d_out;

  const int N = in_sizes[0] / 3;
  const int blocks = (N + WPB - 1) / WPB;
  zono_dist_kernel<<<blocks, WPB * 64, 0, stream>>>(point, Ag, bg, v1g, v2g, out, N);
}

// Round 4
// 60.478 us; speedup vs baseline: 1.5546x; 1.0231x over previous
//
#include <hip/hip_runtime.h>
#include <math.h>
#include <float.h>

// Zonotope distance + gradient. One 64-lane wave per point.
// H=48 hyperplanes, V=96 edges.
// R4: edge payload via async global_load_lds (3x16B/lane) issued at kernel
// top, draining under the H^2 loop; VGPR cap raised to 64; edge reduction
// as value-min + index-min butterflies.
// ALL floating-point op orders match the numpy reference exactly
// (contract(off); no FMA) — the EPS / argmin boundaries are flip-sensitive.

typedef float f32x4 __attribute__((ext_vector_type(4)));

constexpr int H = 48;
constexpr int V = 96;
constexpr int WPB = 4;          // waves per block
constexpr float ZEPS = 1e-4f;

__device__ __forceinline__ void gload_lds16(const void* g, void* lds) {
  __builtin_amdgcn_global_load_lds(
      (const __attribute__((address_space(1))) void*)g,
      (__attribute__((address_space(3))) void*)lds, 16, 0, 0);
}

__global__ __launch_bounds__(256, 8) void zono_dist_kernel(
    const float* __restrict__ point,   // [N,3]
    const float* __restrict__ Ag,      // [N,H,3]
    const float* __restrict__ bg,      // [N,H]
    const float* __restrict__ v1g,     // [N,V,3]
    const float* __restrict__ v2g,     // [N,V,3]
    float* __restrict__ out,           // [N] dist ++ [N,3] grad
    int N)
{
#pragma clang fp contract(off)
  __shared__ __align__(16) float sAb[WPB][192];   // A[48*3] ++ b[48]
  __shared__ __align__(16) float sQx[WPB][48];
  __shared__ __align__(16) float sQy[WPB][48];
  __shared__ __align__(16) float sQz[WPB][48];
  // per wave: v1 = floats [0..287], v2 = [288..575], slop = [576..767]
  __shared__ __align__(16) float sEV[WPB][768];

  const int wave = threadIdx.x >> 6;
  const int lane = threadIdx.x & 63;
  const int n = blockIdx.x * WPB + wave;
  if (n >= N) return;
  const int nu = __builtin_amdgcn_readfirstlane(n);   // uniform -> s_load paths

  // ---- async edge payload -> LDS (in flight under the whole H^2 loop) ----
  // each call writes ldsbase + lane*16 (linear); sources chosen to match.
  {
    const float4* V1f4 = (const float4*)(v1g + (size_t)nu * (V * 3)); // 72 f4
    const float4* V2f4 = (const float4*)(v2g + (size_t)nu * (V * 3)); // 72 f4
    const float4* s1 = V1f4 + lane;                                   // f 0..255
    const float4* s2 = (lane < 8) ? (V1f4 + 64 + lane) : (V2f4 + (lane - 8));
    const float4* s3 = (lane < 16) ? (V2f4 + 56 + lane) : (V2f4 + 71); // clamp->slop
    gload_lds16(s1, &sEV[wave][0]);
    gload_lds16(s2, &sEV[wave][256]);
    gload_lds16(s3, &sEV[wave][512]);
  }

  // ---- point via scalar loads (uniform address) ----
  const float px = point[3 * (size_t)nu + 0];
  const float py = point[3 * (size_t)nu + 1];
  const float pz = point[3 * (size_t)nu + 2];

  // ---- coalesced staging: A (36 float4) + b (12 float4) -> LDS ----
  {
    const float4* Af4 = (const float4*)(Ag + (size_t)nu * (H * 3));
    const float4* Bf4 = (const float4*)(bg + (size_t)nu * H);
    float4* dst = (float4*)sAb[wave];
    if (lane < 36)      dst[lane] = Af4[lane];
    else if (lane < 48) dst[lane] = Bf4[lane - 36];
  }

  // ---- own plane from LDS ----
  float ax = 0.f, ay = 0.f, az = 0.f, bb = 1e30f;  // lanes >=H neutral
  if (lane < H) {
    ax = sAb[wave][3 * lane + 0];
    ay = sAb[wave][3 * lane + 1];
    az = sAb[wave][3 * lane + 2];
    bb = sAb[wave][144 + lane];
  }

  // ---- signed facet offset + projection (exact ref op order) ----
  float apb = -INFINITY;
  float qx = 0.f, qy = 0.f, qz = 0.f;
  if (lane < H) {
    apb = ((ax * px + ay * py) + az * pz) - bb;
    qx = px - apb * ax;
    qy = py - apb * ay;
    qz = pz - apb * az;
    sQx[wave][lane] = qx;
    sQy[wave][lane] = qy;
    sQz[wave][lane] = qz;
  }
  const bool is_neg = (bool)__all(apb <= 0.0f);

  // ---- on-zonotope check, transposed: lane k holds plane k; loop h (x4) ----
  const f32x4 ax4 = {ax, ax, ax, ax}, ay4 = {ay, ay, ay, ay},
              az4 = {az, az, az, az}, bb4 = {bb, bb, bb, bb};
  unsigned long long bad = 0;           // bit h set => on_zono[h] false
  #pragma unroll
  for (int h = 0; h < H; h += 4) {
    f32x4 qx4 = *(const f32x4*)&sQx[wave][h];   // broadcast reads
    f32x4 qy4 = *(const f32x4*)&sQy[wave][h];
    f32x4 qz4 = *(const f32x4*)&sQz[wave][h];
    f32x4 s = ((ax4 * qx4 + ay4 * qy4) + az4 * qz4) - bb4;  // ref einsum order
    unsigned long long b0 = (unsigned long long)(!__all(s.x <= ZEPS));
    unsigned long long b1 = (unsigned long long)(!__all(s.y <= ZEPS));
    unsigned long long b2 = (unsigned long long)(!__all(s.z <= ZEPS));
    unsigned long long b3 = (unsigned long long)(!__all(s.w <= ZEPS));
    bad |= (b0 << h) | (b1 << (h + 1)) | (b2 << (h + 2)) | (b3 << (h + 3));
  }
  const unsigned long long MASK48 = (1ull << H) - 1;
  const bool any_face = ((~bad) & MASK48) != 0;

  // ---- face distance (gated; rare for random data) ----
  float fv = INFINITY; int fi = 0;
  float fgx = 0.f, fgy = 0.f, fgz = 0.f;
  if (any_face) {
    float pv = INFINITY;
    if (lane < H && !((bad >> lane) & 1)) {
      float dx = px - qx, dy = py - qy, dz = pz - qz;   // ref: p - proj
      pv = sqrtf((dx * dx + dy * dy) + dz * dz);
    }
    fv = pv; fi = lane;
    #pragma unroll
    for (int off = 32; off; off >>= 1) {
      float ov = __shfl_xor(fv, off);
      int oi = __shfl_xor(fi, off);
      if (ov < fv || (ov == fv && oi < fi)) { fv = ov; fi = oi; }
    }
    fgx = __shfl(ax, fi); fgy = __shfl(ay, fi); fgz = __shfl(az, fi);
  }

  // ---- inside-zonotope path (gated; rare) ----
  float nv = 0.f;
  float ngx = 0.f, ngy = 0.f, ngz = 0.f;
  if (is_neg) {
    nv = apb; int ni = lane;
    #pragma unroll
    for (int off = 32; off; off >>= 1) {
      float ov = __shfl_xor(nv, off);
      int oi = __shfl_xor(ni, off);
      if (ov > nv || (ov == nv && oi < ni)) { nv = ov; ni = oi; }
    }
    ngx = __shfl(ax, ni); ngy = __shfl(ay, ni); ngz = __shfl(az, ni);
  }

  // ---- drain async edge loads, then edge distances from LDS ----
  asm volatile("s_waitcnt vmcnt(0)" ::: "memory");
  __builtin_amdgcn_sched_barrier(0);

  float bed, bvx, bvy, bvz;
  int bei;
  const float* ev = sEV[wave];
  {
    int e = lane;                                   // round 1: edges 0..63
    float x1 = ev[3 * e + 0], y1 = ev[3 * e + 1], z1 = ev[3 * e + 2];
    float x2 = ev[288 + 3 * e + 0], y2 = ev[288 + 3 * e + 1], z2 = ev[288 + 3 * e + 2];
    float dx = x2 - x1, dy = y2 - y1, dz = z2 - z1;
    float denom = (dx * dx + dy * dy) + dz * dz;
    float wx = px - x1, wy = py - y1, wz = pz - z1;
    float th = ((wx * dx + wy * dy) + wz * dz) / denom;
    float ts = th < 0.0f ? 0.0f : (th > 1.0f ? 1.0f : th);
    float vx = x1 + ts * dx, vy = y1 + ts * dy, vz = z1 + ts * dz;
    float ex = px - vx, ey = py - vy, ez = pz - vz;
    bed = sqrtf((ex * ex + ey * ey) + ez * ez);
    bei = e; bvx = vx; bvy = vy; bvz = vz;
  }
  {
    int e = 64 | (lane & 31);                       // round 2: duplicated, branch-free
    float x1 = ev[3 * e + 0], y1 = ev[3 * e + 1], z1 = ev[3 * e + 2];
    float x2 = ev[288 + 3 * e + 0], y2 = ev[288 + 3 * e + 1], z2 = ev[288 + 3 * e + 2];
    float dx = x2 - x1, dy = y2 - y1, dz = z2 - z1;
    float denom = (dx * dx + dy * dy) + dz * dz;
    float wx = px - x1, wy = py - y1, wz = pz - z1;
    float th = ((wx * dx + wy * dy) + wz * dz) / denom;
    float ts = th < 0.0f ? 0.0f : (th > 1.0f ? 1.0f : th);
    float vx = x1 + ts * dx, vy = y1 + ts * dy, vz = z1 + ts * dz;
    float ex = px - vx, ey = py - vy, ez = pz - vz;
    float ed = sqrtf((ex * ex + ey * ey) + ez * ez);
    if (ed < bed) { bed = ed; bei = e; bvx = vx; bvy = vy; bvz = vz; }
  }
  // value-min butterfly (short dependent chain)
  float m = bed;
  #pragma unroll
  for (int off = 32; off; off >>= 1) {
    float o = __shfl_xor(m, off);
    if (o < m) m = o;
  }
  // index-min among tied lanes (matches argmin first-index tiebreak)
  int sel = (bed == m) ? bei : 0x7FFFFFFF;
  #pragma unroll
  for (int off = 32; off; off >>= 1) {
    int o = __shfl_xor(sel, off);
    if (o < sel) sel = o;
  }
  const int wl = sel & 63;          // lane holding the winning edge's payload
  const float wvx = __shfl(bvx, wl);
  const float wvy = __shfl(bvy, wl);
  const float wvz = __shfl(bvz, wl);

  // ---- combine & write (lane 0) ----
  if (lane == 0) {
    float dist, gx, gy, gz;
    if (is_neg) {
      dist = nv; gx = ngx; gy = ngy; gz = ngz;
    } else if (m < fv) {
      dist = m;
      gx = (px - wvx) / m;
      gy = (py - wvy) / m;
      gz = (pz - wvz) / m;
    } else {
      dist = fv; gx = fgx; gy = fgy; gz = fgz;
    }
    out[n] = dist;
    out[(size_t)N + 3 * (size_t)n + 0] = gx;
    out[(size_t)N + 3 * (size_t)n + 1] = gy;
    out[(size_t)N + 3 * (size_t)n + 2] = gz;
  }
}

extern "C" void kernel_launch(void* const* d_in, const int* in_sizes, int n_in,
                              void* d_out, int out_size, void* d_ws, size_t ws_size,
                              hipStream_t stream) {
  const float* point = (const float*)d_in[0];
  const float* Ag    = (const float*)d_in[1];
  const float* bg    = (const float*)d_in[2];
  const float* v1g   = (const float*)d_in[3];
  const float* v2g   = (const float*)d_in[4];
  float* out = (float*)d_out;

  const int N = in_sizes[0] / 3;
  const int blocks = (N + WPB - 1) / WPB;
  zono_dist_kernel<<<blocks, WPB * 64, 0, stream>>>(point, Ag, bg, v1g, v2g, out, N);
}